// Round 1
// baseline (164.931 us; speedup 1.0000x reference)
//
#include <hip/hip_runtime.h>

// CosineAttention collapses to a linear map:
//   out[q] = (q_hat @ M + u) / (q_hat . s + n)
// with per-(b,h) moments over masked keys:
//   M[j][d] = sum_k m_k khat[k][j] V[k][d]   (64x64)
//   s[j]    = sum_k m_k khat[k][j]
//   u[d]    = sum_k m_k V[k][d]
//   n       = sum_k m_k
// (the (score+1)/2 affine cancels between numerator and denominator)

#define S 4096
#define D 64
#define BH 16            // B*H = 2*8
#define FSTRIDE 4352     // per-(b,h) moment stride in floats (4225 rounded up)
#define NE 4225          // 4096 (M) + 64 (s) + 64 (u) + 1 (n)

__device__ __forceinline__ float rl(float v, int l) {
    return __int_as_float(__builtin_amdgcn_readlane(__float_as_int(v), l));
}

__device__ __forceinline__ float wave_sum(float v) {
    v += __shfl_xor(v, 1, 64);
    v += __shfl_xor(v, 2, 64);
    v += __shfl_xor(v, 4, 64);
    v += __shfl_xor(v, 8, 64);
    v += __shfl_xor(v, 16, 64);
    v += __shfl_xor(v, 32, 64);
    return v;
}

// ---------------- kernel 1: per-chunk partial moments --------------------
// grid (BH, nchunk), block 256 (4 waves). Each wave streams rows, holds a
// full 64x64 M accumulator as 64 regs/lane (lane = d, reg j = M[j][d]).
// Waves merged via LDS; one deterministic partial per block (no atomics).
__global__ __launch_bounds__(256) void k_moments(
    const float* __restrict__ K, const float* __restrict__ V,
    const int* __restrict__ mask, float* __restrict__ part, int nchunk)
{
    const int bh    = blockIdx.x;
    const int chunk = blockIdx.y;
    const int lane  = threadIdx.x & 63;
    const int wave  = threadIdx.x >> 6;

    const int rows_per_block = S / nchunk;
    const int rows = rows_per_block >> 2;           // per wave
    const int row0 = chunk * rows_per_block + wave * rows;

    const float* Kh = K + (size_t)bh * S * D;
    const float* Vh = V + (size_t)bh * S * D;
    const int*   mb = mask + (bh >> 3) * S;         // mask is [B,1,1,S], H=8

    float Macc[64];
    #pragma unroll
    for (int j = 0; j < 64; ++j) Macc[j] = 0.f;
    float s_acc = 0.f, u_acc = 0.f, n_acc = 0.f;

    for (int r = 0; r < rows; ++r) {
        const int row = row0 + r;
        float kd = Kh[(size_t)row * D + lane];
        float vd = Vh[(size_t)row * D + lane];
        float fm = (float)mb[row];                  // 0 or 1, wave-uniform
        float ss = wave_sum(kd * kd);
        float kh = kd * (fm / fmaxf(sqrtf(ss), 1e-12f)); // masked -> 0
        vd *= fm;
        s_acc += kh;
        u_acc += vd;
        n_acc += fm;                                // same in every lane
        #pragma unroll
        for (int j = 0; j < 64; ++j)
            Macc[j] = fmaf(rl(kh, j), vd, Macc[j]);
    }

    __shared__ float red[4096];
    __shared__ float redsu[129];
    if (wave == 0) {
        #pragma unroll
        for (int j = 0; j < 64; ++j) red[j * 64 + lane] = Macc[j];
        redsu[lane] = s_acc;
        redsu[64 + lane] = u_acc;
        if (lane == 0) redsu[128] = n_acc;
    }
    __syncthreads();
    for (int w = 1; w < 4; ++w) {
        if (wave == w) {
            #pragma unroll
            for (int j = 0; j < 64; ++j) red[j * 64 + lane] += Macc[j];
            redsu[lane] += s_acc;
            redsu[64 + lane] += u_acc;
            if (lane == 0) redsu[128] += n_acc;
        }
        __syncthreads();
    }

    float* pp = part + ((size_t)bh * nchunk + chunk) * FSTRIDE;
    for (int i = threadIdx.x; i < NE; i += 256)
        pp[i] = (i < 4096) ? red[i] : redsu[i - 4096];
}

// ---------------- kernel 2: deterministic partial reduction -------------
__global__ __launch_bounds__(256) void k_reduce(
    const float* __restrict__ part, float* __restrict__ fin, int nchunk)
{
    const int bh = blockIdx.x;
    const int e  = blockIdx.y * 256 + threadIdx.x;
    if (e >= NE) return;
    float acc = 0.f;
    for (int c = 0; c < nchunk; ++c)
        acc += part[((size_t)bh * nchunk + c) * FSTRIDE + e];
    fin[(size_t)bh * FSTRIDE + e] = acc;
}

// ---------------- kernel 3: out = (qhat M + u) / (qhat.s + n) -----------
// grid (BH, 32), block 256. Each wave caches M column in 64 VGPRs.
__global__ __launch_bounds__(256) void k_out(
    const float* __restrict__ Q, const float* __restrict__ fin,
    float* __restrict__ out)
{
    const int bh    = blockIdx.x;
    const int chunk = blockIdx.y;
    const int lane  = threadIdx.x & 63;
    const int wave  = threadIdx.x >> 6;

    const float* fb = fin + (size_t)bh * FSTRIDE;
    float Mreg[64];
    #pragma unroll
    for (int j = 0; j < 64; ++j) Mreg[j] = fb[j * 64 + lane];
    float sreg = fb[4096 + lane];
    float ureg = fb[4160 + lane];
    float nval = fb[4224];

    const int rows_per_block = S / 32;              // 128
    const int rows = rows_per_block >> 2;           // 32 per wave
    const int row0 = chunk * rows_per_block + wave * rows;
    const float* Qh = Q + (size_t)bh * S * D;
    float*       Oh = out + (size_t)bh * S * D;

    for (int r = 0; r < rows; ++r) {
        const int row = row0 + r;
        float qd = Qh[(size_t)row * D + lane];
        float ss = wave_sum(qd * qd);
        float inv = 1.f / fmaxf(sqrtf(ss), 1e-12f);
        float qh = qd * inv;
        float den = wave_sum(qh * sreg) + nval;
        float a0 = 0.f, a1 = 0.f, a2 = 0.f, a3 = 0.f;
        #pragma unroll
        for (int j = 0; j < 64; j += 4) {
            a0 = fmaf(rl(qh, j    ), Mreg[j    ], a0);
            a1 = fmaf(rl(qh, j + 1), Mreg[j + 1], a1);
            a2 = fmaf(rl(qh, j + 2), Mreg[j + 2], a2);
            a3 = fmaf(rl(qh, j + 3), Mreg[j + 3], a3);
        }
        float acc = ((a0 + a1) + (a2 + a3)) + ureg;
        Oh[(size_t)row * D + lane] = acc / den;
    }
}

extern "C" void kernel_launch(void* const* d_in, const int* in_sizes, int n_in,
                              void* d_out, int out_size, void* d_ws, size_t ws_size,
                              hipStream_t stream) {
    const float* Q    = (const float*)d_in[0];
    const float* K    = (const float*)d_in[1];
    const float* V    = (const float*)d_in[2];
    const int*   mask = (const int*)d_in[3];
    float* out = (float*)d_out;
    float* ws  = (float*)d_ws;

    float* fin  = ws;                               // BH * FSTRIDE floats
    float* part = ws + (size_t)BH * FSTRIDE;        // BH * nchunk * FSTRIDE

    // Pick largest power-of-two chunk count that fits the workspace.
    int nchunk = 32;
    while (nchunk > 1 &&
           ((size_t)BH * FSTRIDE + (size_t)BH * nchunk * FSTRIDE) * sizeof(float) > ws_size)
        nchunk >>= 1;

    k_moments<<<dim3(BH, nchunk), 256, 0, stream>>>(K, V, mask, part, nchunk);
    k_reduce <<<dim3(BH, (NE + 255) / 256), 256, 0, stream>>>(part, fin, nchunk);
    k_out    <<<dim3(BH, 32), 256, 0, stream>>>(Q, fin, out);
}

// Round 2
// 152.537 us; speedup vs baseline: 1.0813x; 1.0813x over previous
//
#include <hip/hip_runtime.h>

// CosineAttention collapses to a linear map:
//   out[q] = (q_hat @ M + u) / (q_hat . s + n)
// with per-(b,h) moments over masked keys:
//   M[j][d] = sum_k m_k khat[k][j] V[k][d]   (64x64)
//   s[j]    = sum_k m_k khat[k][j]
//   u[d]    = sum_k m_k V[k][d]
//   n       = sum_k m_k
// (the (score+1)/2 affine cancels between numerator and denominator)

#define S 4096
#define D 64
#define BH 16            // B*H = 2*8
#define FSTRIDE 4352     // per-(b,h) moment stride in floats (4225 rounded up)
#define NE 4225          // 4096 (M) + 64 (s) + 64 (u) + 1 (n)

__device__ __forceinline__ float rl(float v, int l) {
    return __int_as_float(__builtin_amdgcn_readlane(__float_as_int(v), l));
}

__device__ __forceinline__ float wave_sum(float v) {
    v += __shfl_xor(v, 1, 64);
    v += __shfl_xor(v, 2, 64);
    v += __shfl_xor(v, 4, 64);
    v += __shfl_xor(v, 8, 64);
    v += __shfl_xor(v, 16, 64);
    v += __shfl_xor(v, 32, 64);
    return v;
}

// ---------------- kernel 1: per-chunk partial moments --------------------
// grid (BH, nchunk), block 256 (4 waves). Each wave streams rows, holds a
// full 64x64 M accumulator as 64 regs/lane (lane = d, reg j = M[j][d]).
// 2 rows per iteration for independent readlane->fma chains (ILP).
__global__ __launch_bounds__(256) void k_moments(
    const float* __restrict__ K, const float* __restrict__ V,
    const int* __restrict__ mask, float* __restrict__ part, int nchunk)
{
    const int bh    = blockIdx.x;
    const int chunk = blockIdx.y;
    const int lane  = threadIdx.x & 63;
    const int wave  = threadIdx.x >> 6;

    const int rows_per_block = S / nchunk;
    const int rows = rows_per_block >> 2;           // per wave (>= 2, even)
    const int row0 = chunk * rows_per_block + wave * rows;

    const float* Kh = K + (size_t)bh * S * D;
    const float* Vh = V + (size_t)bh * S * D;
    const int*   mb = mask + (bh >> 3) * S;         // mask is [B,1,1,S], H=8

    float Macc[64];
    #pragma unroll
    for (int j = 0; j < 64; ++j) Macc[j] = 0.f;
    float s_acc = 0.f, u_acc = 0.f, n_acc = 0.f;

    for (int r = 0; r < rows; r += 2) {
        const int rowA = row0 + r;
        const int rowB = rowA + 1;
        float kA = Kh[(size_t)rowA * D + lane];
        float vA = Vh[(size_t)rowA * D + lane];
        float kB = Kh[(size_t)rowB * D + lane];
        float vB = Vh[(size_t)rowB * D + lane];
        float mA = (float)mb[rowA];
        float mB = (float)mb[rowB];
        float sA = wave_sum(kA * kA);
        float sB = wave_sum(kB * kB);
        float hA = kA * (mA / fmaxf(sqrtf(sA), 1e-12f));  // masked -> 0
        float hB = kB * (mB / fmaxf(sqrtf(sB), 1e-12f));
        vA *= mA;
        vB *= mB;
        s_acc += hA + hB;
        u_acc += vA + vB;
        n_acc += mA + mB;
        #pragma unroll
        for (int j = 0; j < 64; ++j) {
            float t = fmaf(rl(hA, j), vA, Macc[j]);
            Macc[j] = fmaf(rl(hB, j), vB, t);
        }
    }

    __shared__ float red[4096];
    __shared__ float redsu[129];
    if (wave == 0) {
        #pragma unroll
        for (int j = 0; j < 64; ++j) red[j * 64 + lane] = Macc[j];
        redsu[lane] = s_acc;
        redsu[64 + lane] = u_acc;
        if (lane == 0) redsu[128] = n_acc;
    }
    __syncthreads();
    for (int w = 1; w < 4; ++w) {
        if (wave == w) {
            #pragma unroll
            for (int j = 0; j < 64; ++j) red[j * 64 + lane] += Macc[j];
            redsu[lane] += s_acc;
            redsu[64 + lane] += u_acc;
            if (lane == 0) redsu[128] += n_acc;
        }
        __syncthreads();
    }

    float* pp = part + ((size_t)bh * nchunk + chunk) * FSTRIDE;
    for (int i = threadIdx.x; i < NE; i += 256)
        pp[i] = (i < 4096) ? red[i] : redsu[i - 4096];
}

// ---------------- kernel 2: deterministic partial reduction -------------
__global__ __launch_bounds__(256) void k_reduce(
    const float* __restrict__ part, float* __restrict__ fin, int nchunk)
{
    const int bh = blockIdx.x;
    const int e  = blockIdx.y * 256 + threadIdx.x;
    if (e >= NE) return;
    float acc = 0.f;
    for (int c = 0; c < nchunk; ++c)
        acc += part[((size_t)bh * nchunk + c) * FSTRIDE + e];
    fin[(size_t)bh * FSTRIDE + e] = acc;
}

// ---------------- kernel 3: out = (qhat M + u) / (qhat.s + n) -----------
// grid (BH, 64), block 256. Each wave caches M's column in 64 VGPRs,
// PINNED via opaque asm so the compiler cannot rematerialize the loads
// (R1: VGPR_Count=44 proved M was being re-loaded from cache every row).
__global__ __launch_bounds__(256) void k_out(
    const float* __restrict__ Q, const float* __restrict__ fin,
    float* __restrict__ out)
{
    const int bh    = blockIdx.x;
    const int chunk = blockIdx.y;
    const int lane  = threadIdx.x & 63;
    const int wave  = threadIdx.x >> 6;

    const float* fb = fin + (size_t)bh * FSTRIDE;
    float Mreg[64];
    #pragma unroll
    for (int j = 0; j < 64; ++j) Mreg[j] = fb[j * 64 + lane];
    #pragma unroll
    for (int j = 0; j < 64; ++j) asm volatile("" : "+v"(Mreg[j]));
    float sreg = fb[4096 + lane];
    float ureg = fb[4160 + lane];
    float nval = fb[4224];

    const int rows_per_block = S / 64;              // 64
    const int rows = rows_per_block >> 2;           // 16 per wave
    const int row0 = chunk * rows_per_block + wave * rows;
    const float* Qh = Q + (size_t)bh * S * D;
    float*       Oh = out + (size_t)bh * S * D;

    for (int r = 0; r < rows; r += 2) {
        const int rowA = row0 + r;
        const int rowB = rowA + 1;
        float qA = Qh[(size_t)rowA * D + lane];
        float qB = Qh[(size_t)rowB * D + lane];
        float ssA = wave_sum(qA * qA);
        float ssB = wave_sum(qB * qB);
        float hA = qA * (1.f / fmaxf(sqrtf(ssA), 1e-12f));
        float hB = qB * (1.f / fmaxf(sqrtf(ssB), 1e-12f));
        float denA = wave_sum(hA * sreg) + nval;
        float denB = wave_sum(hB * sreg) + nval;
        float a0 = 0.f, a1 = 0.f, a2 = 0.f, a3 = 0.f;
        float b0 = 0.f, b1 = 0.f, b2 = 0.f, b3 = 0.f;
        #pragma unroll
        for (int j = 0; j < 64; j += 4) {
            a0 = fmaf(rl(hA, j    ), Mreg[j    ], a0);
            a1 = fmaf(rl(hA, j + 1), Mreg[j + 1], a1);
            a2 = fmaf(rl(hA, j + 2), Mreg[j + 2], a2);
            a3 = fmaf(rl(hA, j + 3), Mreg[j + 3], a3);
            b0 = fmaf(rl(hB, j    ), Mreg[j    ], b0);
            b1 = fmaf(rl(hB, j + 1), Mreg[j + 1], b1);
            b2 = fmaf(rl(hB, j + 2), Mreg[j + 2], b2);
            b3 = fmaf(rl(hB, j + 3), Mreg[j + 3], b3);
        }
        float accA = ((a0 + a1) + (a2 + a3)) + ureg;
        float accB = ((b0 + b1) + (b2 + b3)) + ureg;
        Oh[(size_t)rowA * D + lane] = accA / denA;
        Oh[(size_t)rowB * D + lane] = accB / denB;
    }
}

extern "C" void kernel_launch(void* const* d_in, const int* in_sizes, int n_in,
                              void* d_out, int out_size, void* d_ws, size_t ws_size,
                              hipStream_t stream) {
    const float* Q    = (const float*)d_in[0];
    const float* K    = (const float*)d_in[1];
    const float* V    = (const float*)d_in[2];
    const int*   mask = (const int*)d_in[3];
    float* out = (float*)d_out;
    float* ws  = (float*)d_ws;

    float* fin  = ws;                               // BH * FSTRIDE floats
    float* part = ws + (size_t)BH * FSTRIDE;        // BH * nchunk * FSTRIDE

    // Pick largest power-of-two chunk count that fits the workspace.
    int nchunk = 64;
    while (nchunk > 1 &&
           ((size_t)BH * FSTRIDE + (size_t)BH * nchunk * FSTRIDE) * sizeof(float) > ws_size)
        nchunk >>= 1;

    k_moments<<<dim3(BH, nchunk), 256, 0, stream>>>(K, V, mask, part, nchunk);
    k_reduce <<<dim3(BH, (NE + 255) / 256), 256, 0, stream>>>(part, fin, nchunk);
    k_out    <<<dim3(BH, 64), 256, 0, stream>>>(Q, fin, out);
}

// Round 3
// 141.094 us; speedup vs baseline: 1.1689x; 1.0811x over previous
//
#include <hip/hip_runtime.h>

// CosineAttention collapses to a linear map:
//   out[q] = (q_hat @ M + u) / (q_hat . s + n)
// with per-(b,h) moments over masked keys:
//   M[j][d] = sum_k m_k khat[k][j] V[k][d]   (64x64)
//   s[j]    = sum_k m_k khat[k][j]
//   u[d]    = sum_k m_k V[k][d]
//   n       = sum_k m_k
// (the (score+1)/2 affine cancels between numerator and denominator)
//
// R3: no per-row wave_sum. Phase A (lane=row) computes row norms / denoms
// with per-lane serial FMAs; Phase B (lane=d) broadcasts them with a single
// readlane per row. ws is ~268 MB (seen via harness 0xAA fill), 18 MB used.

#define S 4096
#define D 64
#define BH 16            // B*H = 2*8
#define FSTRIDE 4352     // per-(b,h) moment stride in floats
#define NE 4225          // 4096 (M) + 64 (s) + 64 (u) + 1 (n)
#define NCH 64           // chunks per head
#define RPB 64           // rows per block
#define RPW 16           // rows per wave

__device__ __forceinline__ float rl(float v, int l) {
    return __int_as_float(__builtin_amdgcn_readlane(__float_as_int(v), l));
}

// ---------------- kernel 1: per-chunk partial moments --------------------
// grid (BH, NCH), block 256 (4 waves).
__global__ __launch_bounds__(256) void k_moments(
    const float* __restrict__ K, const float* __restrict__ V,
    const int* __restrict__ mask, float* __restrict__ part)
{
    const int bh    = blockIdx.x;
    const int chunk = blockIdx.y;
    const int lane  = threadIdx.x & 63;
    const int wave  = threadIdx.x >> 6;
    const int row0  = chunk * RPB;

    const float* Kh = K + (size_t)bh * S * D;
    const float* Vh = V + (size_t)bh * S * D;
    const int*   mb = mask + (bh >> 3) * S;         // mask is [B,1,1,S], H=8

    // ---- Phase A: lane L owns block-row L. No cross-lane ops. ----
    const int rowL = row0 + lane;
    const float mL = (float)mb[rowL];
    float ss = 0.f;
    {
        const float4* kp = (const float4*)(Kh + (size_t)rowL * D);
        #pragma unroll
        for (int d4 = 0; d4 < 16; ++d4) {
            float4 kv = kp[d4];
            ss = fmaf(kv.x, kv.x, ss);
            ss = fmaf(kv.y, kv.y, ss);
            ss = fmaf(kv.z, kv.z, ss);
            ss = fmaf(kv.w, kv.w, ss);
        }
    }
    const float minvL = mL / fmaxf(sqrtf(ss), 1e-12f);   // masked -> 0

    // ---- Phase B: lane = d. Wave w handles rows [w*16, w*16+16). ----
    float Macc[64];
    #pragma unroll
    for (int j = 0; j < 64; ++j) Macc[j] = 0.f;
    float s_acc = 0.f, u_acc = 0.f, n_acc = 0.f;

    #pragma unroll
    for (int r = 0; r < RPW; ++r) {
        const int src = wave * RPW + r;        // lane owning this row
        const int row = row0 + src;
        float kd = Kh[(size_t)row * D + lane];
        float vd = Vh[(size_t)row * D + lane];
        float aj = rl(minvL, src);             // m/norm, wave-uniform
        float mj = rl(mL, src);
        float kh = kd * aj;
        float vm = vd * mj;
        s_acc += kh;
        u_acc += vm;
        n_acc += mj;
        #pragma unroll
        for (int j = 0; j < 64; ++j)
            Macc[j] = fmaf(rl(kh, j), vm, Macc[j]);
    }

    // ---- cross-wave merge (deterministic) ----
    __shared__ float red[4096];
    __shared__ float redsu[129];
    if (wave == 0) {
        #pragma unroll
        for (int j = 0; j < 64; ++j) red[j * 64 + lane] = Macc[j];
        redsu[lane] = s_acc;
        redsu[64 + lane] = u_acc;
        if (lane == 0) redsu[128] = n_acc;
    }
    __syncthreads();
    for (int w = 1; w < 4; ++w) {
        if (wave == w) {
            #pragma unroll
            for (int j = 0; j < 64; ++j) red[j * 64 + lane] += Macc[j];
            redsu[lane] += s_acc;
            redsu[64 + lane] += u_acc;
            if (lane == 0) redsu[128] += n_acc;
        }
        __syncthreads();
    }

    float* pp = part + ((size_t)bh * NCH + chunk) * FSTRIDE;
    for (int i = threadIdx.x; i < NE; i += 256)
        pp[i] = (i < 4096) ? red[i] : redsu[i - 4096];
}

// ---------------- kernel 2: deterministic partial reduction -------------
__global__ __launch_bounds__(256) void k_reduce(
    const float* __restrict__ part, float* __restrict__ fin)
{
    const int bh = blockIdx.x;
    const int e  = blockIdx.y * 256 + threadIdx.x;
    if (e >= NE) return;
    const float* p = part + (size_t)bh * NCH * FSTRIDE + e;
    float a0 = 0.f, a1 = 0.f, a2 = 0.f, a3 = 0.f;
    #pragma unroll
    for (int c = 0; c < NCH; c += 4) {
        a0 += p[(size_t)(c + 0) * FSTRIDE];
        a1 += p[(size_t)(c + 1) * FSTRIDE];
        a2 += p[(size_t)(c + 2) * FSTRIDE];
        a3 += p[(size_t)(c + 3) * FSTRIDE];
    }
    fin[(size_t)bh * FSTRIDE + e] = (a0 + a1) + (a2 + a3);
}

// ---------------- kernel 3: out = (qhat M + u) / (qhat.s + n) -----------
// grid (BH, NCH), block 256. M pinned in 64 VGPRs per lane.
__global__ __launch_bounds__(256) void k_out(
    const float* __restrict__ Q, const float* __restrict__ fin,
    float* __restrict__ out)
{
    const int bh    = blockIdx.x;
    const int chunk = blockIdx.y;
    const int lane  = threadIdx.x & 63;
    const int wave  = threadIdx.x >> 6;
    const int row0  = chunk * RPB;

    const float* fb = fin + (size_t)bh * FSTRIDE;
    const float sreg = fb[4096 + lane];
    const float ureg = fb[4160 + lane];
    const float nval = fb[4224];
    const float* Qh = Q + (size_t)bh * S * D;
    float*       Oh = out + (size_t)bh * S * D;

    // ---- Phase A: lane L owns block-row L: norm + denominator. ----
    const int rowL = row0 + lane;
    float ss = 0.f, qs = 0.f;
    {
        const float4* qp = (const float4*)(Qh + (size_t)rowL * D);
        #pragma unroll
        for (int d4 = 0; d4 < 16; ++d4) {
            float4 qv = qp[d4];
            float s0 = rl(sreg, 4 * d4    );
            float s1 = rl(sreg, 4 * d4 + 1);
            float s2 = rl(sreg, 4 * d4 + 2);
            float s3 = rl(sreg, 4 * d4 + 3);
            ss = fmaf(qv.x, qv.x, ss);
            ss = fmaf(qv.y, qv.y, ss);
            ss = fmaf(qv.z, qv.z, ss);
            ss = fmaf(qv.w, qv.w, ss);
            qs = fmaf(qv.x, s0, qs);
            qs = fmaf(qv.y, s1, qs);
            qs = fmaf(qv.z, s2, qs);
            qs = fmaf(qv.w, s3, qs);
        }
    }
    const float invL  = 1.f / fmaxf(sqrtf(ss), 1e-12f);
    const float denL  = fmaf(qs, invL, nval);
    const float rdenL = 1.f / denL;            // accurate division, per row

    // ---- M column into pinned VGPRs ----
    float Mreg[64];
    #pragma unroll
    for (int j = 0; j < 64; ++j) Mreg[j] = fb[j * 64 + lane];
    #pragma unroll
    for (int j = 0; j < 64; ++j) asm volatile("" : "+v"(Mreg[j]));

    // ---- Phase B: lane = d. Wave w handles rows [w*16, w*16+16). ----
    #pragma unroll
    for (int r = 0; r < RPW; ++r) {
        const int src = wave * RPW + r;
        const int row = row0 + src;
        float qd   = Qh[(size_t)row * D + lane];
        float invr = rl(invL, src);
        float rden = rl(rdenL, src);
        float qh   = qd * invr;
        float a0 = 0.f, a1 = 0.f, a2 = 0.f, a3 = 0.f;
        #pragma unroll
        for (int j = 0; j < 64; j += 4) {
            a0 = fmaf(rl(qh, j    ), Mreg[j    ], a0);
            a1 = fmaf(rl(qh, j + 1), Mreg[j + 1], a1);
            a2 = fmaf(rl(qh, j + 2), Mreg[j + 2], a2);
            a3 = fmaf(rl(qh, j + 3), Mreg[j + 3], a3);
        }
        float acc = ((a0 + a1) + (a2 + a3)) + ureg;
        Oh[(size_t)row * D + lane] = acc * rden;
    }
}

extern "C" void kernel_launch(void* const* d_in, const int* in_sizes, int n_in,
                              void* d_out, int out_size, void* d_ws, size_t ws_size,
                              hipStream_t stream) {
    const float* Q    = (const float*)d_in[0];
    const float* K    = (const float*)d_in[1];
    const float* V    = (const float*)d_in[2];
    const int*   mask = (const int*)d_in[3];
    float* out = (float*)d_out;
    float* ws  = (float*)d_ws;

    float* fin  = ws;                               // BH * FSTRIDE floats
    float* part = ws + (size_t)BH * FSTRIDE;        // BH * NCH * FSTRIDE

    k_moments<<<dim3(BH, NCH), 256, 0, stream>>>(K, V, mask, part);
    k_reduce <<<dim3(BH, (NE + 255) / 256), 256, 0, stream>>>(part, fin);
    k_out    <<<dim3(BH, NCH), 256, 0, stream>>>(Q, fin, out);
}